// Round 4
// baseline (4135.742 us; speedup 1.0000x reference)
//
#include <hip/hip_runtime.h>

typedef __bf16 bf16;
typedef __attribute__((ext_vector_type(8))) __bf16 bf16x8;
typedef __attribute__((ext_vector_type(4))) __bf16 bf16x4;
typedef __attribute__((ext_vector_type(4))) float f32x4;

#define HD 256
#define GEMM_GELU 2

// fast gelu: tanh form via hardware exp. |err vs exact erf-gelu| <= ~0.004,
// well inside the bf16 tolerance; ~8 VALU ops vs ~30 for erff.
__device__ __forceinline__ float gelu_f(float x) {
  float x2 = x * x;
  float u = 1.5957691216057308f * x * fmaf(0.044715f, x2, 1.0f);
  float e = __expf(-u);               // v_exp_f32
  return x / (1.0f + e);              // x * sigmoid(u)
}

__device__ __forceinline__ void gload_lds16(const void* g, void* l) {
  __builtin_amdgcn_global_load_lds(
      (const __attribute__((address_space(1))) unsigned int*)g,
      (__attribute__((address_space(3))) unsigned int*)l, 16, 0, 0);
}

// ---------------- GEMM: C[M,N] = act(A[M,K] @ W[K,N] + bias) ----------------
// A: [M,*] bf16 row-stride lda.  Wt: [N,Kd] bf16 (pre-transposed, contiguous).
// C: [M,*] bf16 row-stride ldc.  N = gridDim.x*128 (multiple of 128).
// 128x128 tile, 4 waves, 4x4 of 16x16x32 MFMA (operands swapped).
// v5: BARRIER-FREE per-wave pipelines. Rounds 1-3 (drain dbuf / counted-vmcnt
// depth-2 / BK=64 depth-1) all converged to 2.5-2.7 TB/s with ~2500 cyc/iter of
// unattributed stall -> lockstep block barriers convoy the 8 waves/CU. Fix:
//  - B (Wt, <=786 KB, L2-resident) loaded straight to REGISTERS, dbl-buffered.
//  - each wave stages its OWN 64 A-rows into a private LDS slab (ring-2).
//  - no LDS sharing between waves -> ZERO barriers in the K-loop; each wave
//    waits only on its own vmcnt(16) and free-runs at its own phase.
// Same fragment math as v4 (XOR chunk swizzle) -> bit-identical output.
__global__ __launch_bounds__(256) void gemm_k(
    const bf16* __restrict__ A, const bf16* __restrict__ Wt,
    const float* __restrict__ bias, bf16* __restrict__ C,
    int M, int Kd, int lda, int ldc, int flags)
{
  __shared__ __align__(16) bf16 sA[2][4][64 * 64];   // [ring][wave][row][k] 64 KB
  const int t = threadIdx.x;
  const int lane = t & 63, w = t >> 6;
  const int n0 = blockIdx.x * 128, m0 = blockIdx.y * 128;
  const int wr = w >> 1, wc = w & 1;
  const int lm = lane & 15, quad = lane >> 4;
  const int rowl = lane >> 3;                    // 0..7 within an 8-row group
  const int gcl = (lane & 7) ^ rowl;             // source chunk (16 B units)
  const bool full = (m0 + 128 <= M);

  // A staging: wave stages rows [wr*64, wr*64+64); instr i covers rows i*8+rowl,
  // 8 lanes/row fetch one aligned 128 B region (XOR-permuted lane->chunk).
  const char* pa = (const char*)(A + (size_t)(m0 + wr * 64 + rowl) * lda) + gcl * 16;
  const size_t stepA = (size_t)8 * lda * 2;      // 8 rows, bytes
  // B: per-lane base for row n0 + wc*64 + lm, k-chunk quad*8
  const bf16* pbL = Wt + (size_t)(n0 + wc * 64 + lm) * Kd + quad * 8;

  bf16* buf0 = &sA[0][w][0];
  bf16* buf1 = &sA[1][w][0];

  f32x4 acc[4][4];
#pragma unroll
  for (int i = 0; i < 4; i++)
#pragma unroll
    for (int j = 0; j < 4; j++)
#pragma unroll
      for (int r = 0; r < 4; r++) acc[i][j][r] = 0.f;

  const int nk = Kd >> 6;   // K-tiles of 64 (Kd is 256/1024/1536 -> nk even, >=4)

  bf16x8 bA[2][4], bB[2][4];   // two B register buffers, [s][j]

  auto loadB = [&](int kt, bf16x8 (&bb)[2][4]) {   // 8 global loads (L2-hit)
#pragma unroll
    for (int s = 0; s < 2; s++)
#pragma unroll
      for (int j = 0; j < 4; j++)
        bb[s][j] = *(const bf16x8*)(pbL + (size_t)j * 16 * Kd + (size_t)kt * 64 + s * 32);
  };
  auto stageA = [&](bf16* buf, int kt) {           // 8 gload_lds, own slab
    size_t ko = (size_t)kt * 128;                  // 64 k-elems * 2 B
#pragma unroll
    for (int i = 0; i < 8; i++)
      gload_lds16(pa + i * stepA + ko, buf + i * 512);
  };
  auto compute = [&](const bf16* buf, bf16x8 (&bb)[2][4]) {
#pragma unroll
    for (int s = 0; s < 2; s++) {
      bf16x8 af[4];
#pragma unroll
      for (int i = 0; i < 4; i++)
        af[i] = *(const bf16x8*)(buf + (i * 16 + lm) * 64 + ((s * 4 + quad) ^ (lm & 7)) * 8);
      // swapped operands: D[n][m] -> acc[i][j] row = n (quad*4+r), col = m (lm)
#pragma unroll
      for (int i = 0; i < 4; i++)
#pragma unroll
        for (int j = 0; j < 4; j++)
          acc[i][j] = __builtin_amdgcn_mfma_f32_16x16x32_bf16(bb[s][j], af[i], acc[i][j], 0, 0, 0);
    }
  };

  if (full) {
    // per-wave software pipeline, no barriers. Issue order (in-order vmcnt):
    // B0 A0 B1 A1 | [wait16 C0 B2 A2] [wait16 C1 B3 A3] | ... | wait0 Clast
    loadB(0, bA); stageA(buf0, 0);
    loadB(1, bB); stageA(buf1, 1);
    for (int kt = 0; kt < nk; kt += 2) {
      if (kt + 1 < nk) { asm volatile("s_waitcnt vmcnt(16)" ::: "memory"); }
      else             { asm volatile("s_waitcnt vmcnt(0)" ::: "memory"); }
      compute(buf0, bA);
      if (kt + 2 < nk) { loadB(kt + 2, bA); stageA(buf0, kt + 2); }
      if (kt + 2 < nk) { asm volatile("s_waitcnt vmcnt(16)" ::: "memory"); }
      else             { asm volatile("s_waitcnt vmcnt(0)" ::: "memory"); }
      compute(buf1, bB);
      if (kt + 3 < nk) { loadB(kt + 3, bB); stageA(buf1, kt + 3); }
    }
  } else {
    // tail block-row (M%128): per-wave, reg-staged A with bounds check, no barriers.
    for (int kt = 0; kt < nk; ++kt) {
      size_t ko = (size_t)kt * 64;   // elements
      loadB(kt, bA);
#pragma unroll
      for (int i = 0; i < 8; i++) {
        int gr = m0 + wr * 64 + i * 8 + rowl;
        bf16x8 va;
#pragma unroll
        for (int q = 0; q < 8; q++) va[q] = (bf16)0.f;
        if (gr < M) va = *(const bf16x8*)(A + (size_t)gr * lda + ko + gcl * 8);
        *(bf16x8*)(buf0 + i * 512 + lane * 8) = va;
      }
      compute(buf0, bA);
    }
  }

  // epilogue: thread (quad,lm) holds rows m0+wr*64+i*16+lm, cols n0+wc*64+j*16+quad*4+r
  float4 bia[4];
#pragma unroll
  for (int j = 0; j < 4; j++)
    bia[j] = *(const float4*)(bias + n0 + wc * 64 + j * 16 + quad * 4);
#pragma unroll
  for (int i = 0; i < 4; i++) {
    int gr = m0 + wr * 64 + i * 16 + lm;
    if (gr < M) {
      bf16* crow = C + (size_t)gr * ldc;
#pragma unroll
      for (int j = 0; j < 4; j++) {
        int gc = n0 + wc * 64 + j * 16 + quad * 4;
        float v0 = acc[i][j][0] + bia[j].x;
        float v1 = acc[i][j][1] + bia[j].y;
        float v2 = acc[i][j][2] + bia[j].z;
        float v3 = acc[i][j][3] + bia[j].w;
        if (flags & GEMM_GELU) {
          v0 = gelu_f(v0); v1 = gelu_f(v1); v2 = gelu_f(v2); v3 = gelu_f(v3);
        }
        bf16x4 o = {(bf16)v0, (bf16)v1, (bf16)v2, (bf16)v3};
        *(bf16x4*)(crow + gc) = o;
      }
    }
  }
}

// ---------------- segment sum via CSR (strided rows) ----------------
__global__ __launch_bounds__(256) void segsum_k(
    const int* __restrict__ offs, const int* __restrict__ cols,
    const bf16* __restrict__ in, int ldin, bf16* __restrict__ out, int ldout, int nseg)
{
  int wid = threadIdx.x >> 6, lane = threadIdx.x & 63;
  int seg = blockIdx.x * 4 + wid;
  if (seg >= nseg) return;
  int b = offs[seg], e = offs[seg + 1];
  float a0 = 0.f, a1 = 0.f, a2 = 0.f, a3 = 0.f;
  for (int i = b; i < e; i++) {
    int c = cols[i];
    bf16x4 v = *(const bf16x4*)(in + (size_t)c * ldin + lane * 4);
    a0 += (float)v.x; a1 += (float)v.y; a2 += (float)v.z; a3 += (float)v.w;
  }
  bf16x4 o = {(bf16)a0, (bf16)a1, (bf16)a2, (bf16)a3};
  *(bf16x4*)(out + (size_t)seg * ldout + lane * 4) = o;
}

// ---------------- fused residual + (gelu) + LayerNorm ----------------
__global__ __launch_bounds__(256) void ln_k(
    const bf16* __restrict__ X, int ldx, const bf16* __restrict__ A,
    const float* __restrict__ gam, const float* __restrict__ bet,
    bf16* __restrict__ outb, float* __restrict__ outf, int M, int apply_gelu)
{
  int wid = threadIdx.x >> 6, lane = threadIdx.x & 63;
  int row = blockIdx.x * 4 + wid;
  if (row >= M) return;
  size_t xbase = (size_t)row * ldx + lane * 4;
  size_t abase = (size_t)row * HD + lane * 4;
  bf16x4 xv = *(const bf16x4*)(X + xbase);
  bf16x4 av = *(const bf16x4*)(A + abase);
  float s0, s1, s2, s3;
  if (apply_gelu) {
    s0 = (float)xv.x + gelu_f((float)av.x);
    s1 = (float)xv.y + gelu_f((float)av.y);
    s2 = (float)xv.z + gelu_f((float)av.z);
    s3 = (float)xv.w + gelu_f((float)av.w);
  } else {
    s0 = (float)xv.x + (float)av.x;
    s1 = (float)xv.y + (float)av.y;
    s2 = (float)xv.z + (float)av.z;
    s3 = (float)xv.w + (float)av.w;
  }
  float sum = s0 + s1 + s2 + s3;
#pragma unroll
  for (int o = 32; o; o >>= 1) sum += __shfl_xor(sum, o, 64);
  float mean = sum * (1.0f / 256.0f);
  float d0 = s0 - mean, d1 = s1 - mean, d2 = s2 - mean, d3 = s3 - mean;
  float vs = d0 * d0 + d1 * d1 + d2 * d2 + d3 * d3;
#pragma unroll
  for (int o = 32; o; o >>= 1) vs += __shfl_xor(vs, o, 64);
  float rstd = rsqrtf(vs * (1.0f / 256.0f) + 1e-5f);
  float4 g = *(const float4*)(gam + lane * 4);
  float4 bb = *(const float4*)(bet + lane * 4);
  float y0 = d0 * rstd * g.x + bb.x;
  float y1 = d1 * rstd * g.y + bb.y;
  float y2 = d2 * rstd * g.z + bb.z;
  float y3 = d3 * rstd * g.w + bb.w;
  if (outb) {
    bf16x4 o = {(bf16)y0, (bf16)y1, (bf16)y2, (bf16)y3};
    *(bf16x4*)(outb + xbase) = o;
  }
  if (outf) {
    float4 o = {y0, y1, y2, y3};
    *(float4*)(outf + abase) = o;
  }
}

// ---------------- lg_x init ----------------
__global__ __launch_bounds__(256) void gather_rel_k(
    const int* __restrict__ feat, const float* __restrict__ rel,
    bf16* __restrict__ out, int ldout, int NE)
{
  int wid = threadIdx.x >> 6, lane = threadIdx.x & 63;
  int e = blockIdx.x * 4 + wid;
  if (e >= NE) return;
  int f = feat[e];
  float4 v = *(const float4*)(rel + (size_t)f * HD + lane * 4);
  bf16x4 o = {(bf16)v.x, (bf16)v.y, (bf16)v.z, (bf16)v.w};
  *(bf16x4*)(out + (size_t)e * ldout + lane * 4) = o;
}

// ---------------- fused_edges: out[e] = x[src[e]] + x[dst[e]] ----------------
__global__ __launch_bounds__(256) void gather2_k(
    const int* __restrict__ src, const int* __restrict__ dst,
    const bf16* __restrict__ x, int ldx, bf16* __restrict__ out, int ldout, int NE)
{
  int wid = threadIdx.x >> 6, lane = threadIdx.x & 63;
  int e = blockIdx.x * 4 + wid;
  if (e >= NE) return;
  int s = src[e], d = dst[e];
  bf16x4 a = *(const bf16x4*)(x + (size_t)s * ldx + lane * 4);
  bf16x4 b = *(const bf16x4*)(x + (size_t)d * ldx + lane * 4);
  bf16x4 o = {(bf16)((float)a.x + (float)b.x), (bf16)((float)a.y + (float)b.y),
              (bf16)((float)a.z + (float)b.z), (bf16)((float)a.w + (float)b.w)};
  *(bf16x4*)(out + (size_t)e * ldout + lane * 4) = o;
}

// ---------------- f32 row copy -> bf16 strided ----------------
__global__ __launch_bounds__(256) void f2b_k(const float* __restrict__ in,
                                             bf16* __restrict__ out, int ldout, int M) {
  int wid = threadIdx.x >> 6, lane = threadIdx.x & 63;
  int row = blockIdx.x * 4 + wid;
  if (row >= M) return;
  float4 v = *(const float4*)(in + (size_t)row * HD + lane * 4);
  bf16x4 o = {(bf16)v.x, (bf16)v.y, (bf16)v.z, (bf16)v.w};
  *(bf16x4*)(out + (size_t)row * ldout + lane * 4) = o;
}

// ---------------- weight transpose+convert ----------------
__global__ __launch_bounds__(256) void wtrans_k(const float* __restrict__ in, bf16* __restrict__ out,
                                                int Kd, int Nd) {
  size_t moff = (size_t)blockIdx.y * Kd * Nd;
  int id = blockIdx.x * 256 + threadIdx.x;
  if (id >= Kd * Nd) return;
  int n = id / Kd, k = id - n * Kd;
  out[moff + id] = (bf16)in[moff + (size_t)k * Nd + n];
}

// ---------------- cat weight build ----------------
__global__ __launch_bounds__(256) void wcat_k(const float* __restrict__ ws, const float* __restrict__ wk,
                                              const float* __restrict__ wf, bf16* __restrict__ out,
                                              int KH, int CW) {
  int mi = blockIdx.y;
  int id = blockIdx.x * 256 + threadIdx.x;
  if (id >= HD * CW) return;
  int n = id / CW, k = id - n * CW;
  int s = k >> 8, kk = k & 255;
  float v;
  if (s == 0)       v = ws[((size_t)mi * HD + kk) * HD + n];
  else if (s <= KH) v = wk[(((size_t)mi * KH + (s - 1)) * HD + kk) * HD + n];
  else              v = wf[((size_t)mi * HD + kk) * HD + n];
  out[(size_t)mi * HD * CW + id] = (bf16)v;
}

// ---------------- cat bias ----------------
__global__ __launch_bounds__(256) void bcat_k(const float* __restrict__ bs, const float* __restrict__ bk,
                                              const float* __restrict__ bf, float* __restrict__ out, int KH) {
  int mi = blockIdx.x, n = threadIdx.x;
  float v = bs[(size_t)mi * HD + n] + bf[(size_t)mi * HD + n];
  for (int i = 0; i < KH; i++) v += bk[((size_t)mi * KH + i) * HD + n];
  out[(size_t)mi * HD + n] = v;
}

// ---------------- CSR build ----------------
__global__ __launch_bounds__(256) void count_k(const int* __restrict__ keys, int n, int* __restrict__ cnt) {
  int i = blockIdx.x * 256 + threadIdx.x;
  if (i < n) atomicAdd(&cnt[keys[i]], 1);
}
__global__ __launch_bounds__(256) void scan1_k(const int* __restrict__ in, int* __restrict__ out,
                                               int* __restrict__ bsum, int n) {
  __shared__ int sh[256];
  int t = threadIdx.x;
  int i0 = blockIdx.x * 1024 + t * 4;
  int v0 = (i0 < n) ? in[i0] : 0;
  int v1 = (i0 + 1 < n) ? in[i0 + 1] : 0;
  int v2 = (i0 + 2 < n) ? in[i0 + 2] : 0;
  int v3 = (i0 + 3 < n) ? in[i0 + 3] : 0;
  int tsum = v0 + v1 + v2 + v3;
  sh[t] = tsum;
  __syncthreads();
  for (int o = 1; o < 256; o <<= 1) {
    int x = (t >= o) ? sh[t - o] : 0;
    __syncthreads();
    sh[t] += x;
    __syncthreads();
  }
  int e0 = sh[t] - tsum;
  if (t == 255) bsum[blockIdx.x] = sh[255];
  if (i0 < n) out[i0] = e0;
  e0 += v0;
  if (i0 + 1 < n) out[i0 + 1] = e0;
  e0 += v1;
  if (i0 + 2 < n) out[i0 + 2] = e0;
  e0 += v2;
  if (i0 + 3 < n) out[i0 + 3] = e0;
}
__global__ void scan2_k(int* bsum, int nb, int* total) {
  if (threadIdx.x == 0 && blockIdx.x == 0) {
    int acc = 0;
    for (int i = 0; i < nb; i++) { int v = bsum[i]; bsum[i] = acc; acc += v; }
    *total = acc;
  }
}
__global__ __launch_bounds__(256) void scan3_k(int* out, const int* bsum, int n) {
  int i = blockIdx.x * 256 + threadIdx.x;
  if (i < n) out[i] += bsum[i >> 10];
}
__global__ __launch_bounds__(256) void fill_k(const int* __restrict__ keys, const int* __restrict__ vals,
                                              int n, int modE, int* __restrict__ cursor, int* __restrict__ cols) {
  int i = blockIdx.x * 256 + threadIdx.x;
  if (i >= n) return;
  int pos = atomicAdd(&cursor[keys[i]], 1);
  cols[pos] = vals ? vals[i] : (i < modE ? i : i - modE);
}

extern "C" void kernel_launch(void* const* d_in, const int* in_sizes, int n_in,
                              void* d_out, int out_size, void* d_ws, size_t ws_size,
                              hipStream_t stream)
{
  const float* x_in      = (const float*)d_in[0];
  const int*   edge_feat = (const int*)d_in[1];
  const int*   eig       = (const int*)d_in[2];
  const int*   eil       = (const int*)d_in[3];
  const float* rel       = (const float*)d_in[4];
  const float* w_self = (const float*)d_in[5];
  const float* b_self = (const float*)d_in[6];
  const float* w_khop = (const float*)d_in[7];
  const float* b_khop = (const float*)d_in[8];
  const float* w_fuse = (const float*)d_in[9];
  const float* b_fuse = (const float*)d_in[10];
  const float* w_ff1  = (const float*)d_in[11];
  const float* b_ff1  = (const float*)d_in[12];
  const float* w_ff2  = (const float*)d_in[13];
  const float* b_ff2  = (const float*)d_in[14];
  const float* ln1_g  = (const float*)d_in[15];
  const float* ln1_b  = (const float*)d_in[16];
  const float* ln2_g  = (const float*)d_in[17];
  const float* ln2_b  = (const float*)d_in[18];

  const int NN = in_sizes[0] / HD;
  const int NE = in_sizes[1];
  const int NL = in_sizes[3] / 2;
  const int L  = in_sizes[5] / (2 * HD * HD);
  const int KH = in_sizes[7] / (L * 2 * HD * HD);
  const int CW = (KH + 2) * HD;   // cat width: x | z1..zKH | fused

  char* p = (char*)d_ws;
  auto alloc = [&](size_t bytes) -> void* {
    void* r = (void*)p;
    p += (bytes + 255) & ~(size_t)255;
    return r;
  };

  bf16* n_cat  = (bf16*)alloc((size_t)NN * CW * 2);
  bf16* lg_cat = (bf16*)alloc((size_t)NE * CW * 2);
  bf16* acc_n  = (bf16*)alloc((size_t)NN * HD * 2);
  bf16* acc_e  = (bf16*)alloc((size_t)NE * HD * 2);

  bf16*  wcat_t = (bf16*)alloc((size_t)L * 2 * HD * CW * 2);
  float* bcat   = (float*)alloc((size_t)L * 2 * HD * 4);
  bf16*  wff1_t = (bf16*)alloc((size_t)L * 2 * HD * 4 * HD * 2);
  bf16*  wff2_t = (bf16*)alloc((size_t)L * 2 * HD * 4 * HD * 2);

  int* inc_offs = (int*)alloc((size_t)(NN + 1) * 4);
  int* inc_cur  = (int*)alloc((size_t)NN * 4);
  int* inc_cols = (int*)alloc((size_t)2 * NE * 4);
  int* ng_offs  = (int*)alloc((size_t)(NN + 1) * 4);
  int* ng_cur   = (int*)alloc((size_t)NN * 4);
  int* ng_cols  = (int*)alloc((size_t)NE * 4);
  int* lg_offs  = (int*)alloc((size_t)(NE + 1) * 4);
  int* lg_cur   = (int*)alloc((size_t)NE * 4);
  int* lg_cols  = (int*)alloc((size_t)NL * 4);
  int* bsum     = (int*)alloc(3 * 256 * 4);

  // ---- weights ----
  wcat_k<<<dim3((HD * CW + 255) / 256, L * 2), 256, 0, stream>>>(w_self, w_khop, w_fuse, wcat_t, KH, CW);
  bcat_k<<<L * 2, 256, 0, stream>>>(b_self, b_khop, b_fuse, bcat, KH);
  wtrans_k<<<dim3((HD * 4 * HD + 255) / 256, L * 2), 256, 0, stream>>>(w_ff1, wff1_t, HD, 4 * HD);
  wtrans_k<<<dim3((HD * 4 * HD + 255) / 256, L * 2), 256, 0, stream>>>(w_ff2, wff2_t, 4 * HD, HD);

  // ---- activation init ----
  f2b_k<<<(NN + 3) / 4, 256, 0, stream>>>(x_in, n_cat, CW, NN);
  gather_rel_k<<<(NE + 3) / 4, 256, 0, stream>>>(edge_feat, rel, lg_cat, CW, NE);

  // ---- CSR builds ----
  auto build_csr = [&](const int* keys, int nkeys, const int* vals, int modE,
                       int nseg, int* offs, int* cur, int* cols, int* bs) {
    int nb = (nseg + 1023) / 1024;
    hipMemsetAsync(offs, 0, (size_t)(nseg + 1) * 4, stream);
    count_k<<<(nkeys + 255) / 256, 256, 0, stream>>>(keys, nkeys, offs);
    scan1_k<<<nb, 256, 0, stream>>>(offs, offs, bs, nseg);
    scan2_k<<<1, 1, 0, stream>>>(bs, nb, offs + nseg);
    scan3_k<<<(nseg + 255) / 256, 256, 0, stream>>>(offs, bs, nseg);
    hipMemcpyAsync(cur, offs, (size_t)nseg * 4, hipMemcpyDeviceToDevice, stream);
    fill_k<<<(nkeys + 255) / 256, 256, 0, stream>>>(keys, vals, nkeys, modE, cur, cols);
  };
  build_csr(eig, 2 * NE, nullptr, NE, NN, inc_offs, inc_cur, inc_cols, bsum);
  build_csr(eig + NE, NE, eig, 0, NN, ng_offs, ng_cur, ng_cols, bsum + 256);
  build_csr(eil + NL, NL, eil, 0, NE, lg_offs, lg_cur, lg_cols, bsum + 512);

  float* out_x  = (float*)d_out;
  float* out_lg = (float*)d_out + (size_t)NN * HD;

  auto run_core = [&](bf16* cat, bf16* accb, const int* coffs, const int* ccols,
                      int M, int l, int c, float* outf) {
    size_t mi = (size_t)(l * 2 + c);
    int mb = (M + 127) / 128;
    // khop chain into slices 1..KH
    for (int i = 1; i <= KH; i++)
      segsum_k<<<(M + 3) / 4, 256, 0, stream>>>(coffs, ccols, cat + (size_t)(i - 1) * HD, CW,
                                                cat + (size_t)i * HD, CW, M);
    // acc = cat @ Wcat + bcat   (self + khops + fuse, one K=1536 GEMM)
    gemm_k<<<dim3(2, mb), 256, 0, stream>>>(cat, wcat_t + mi * HD * CW, bcat + mi * HD,
                                            accb, M, CW, CW, HD, 0);
    // t = LN1(x + gelu(acc)) -> slice0
    ln_k<<<(M + 3) / 4, 256, 0, stream>>>(cat, CW, accb, ln1_g + mi * HD, ln1_b + mi * HD,
                                          cat, (float*)nullptr, M, 1);
    // FFN, chunked through a reused scratch region (rows 0..FC of slices 1..4)
    // so the hidden chunk stays LLC-resident instead of round-tripping HBM.
    bf16* hid = cat + HD;                 // scratch: slice1..4, rows [0, FC)
    int FC = (M > 40000) ? 40000 : M;
    for (int c0 = 0; c0 < M; c0 += FC) {
      int mc = (M - c0 < FC) ? (M - c0) : FC;
      int mbc = (mc + 127) / 128;
      gemm_k<<<dim3(8, mbc), 256, 0, stream>>>(cat + (size_t)c0 * CW, wff1_t + mi * HD * 4 * HD,
                                               b_ff1 + mi * 4 * HD, hid, mc, HD, CW, CW, GEMM_GELU);
      gemm_k<<<dim3(2, mbc), 256, 0, stream>>>(hid, wff2_t + mi * 4 * HD * HD, b_ff2 + mi * HD,
                                               accb + (size_t)c0 * HD, mc, 4 * HD, CW, HD, 0);
    }
    // x_new = LN2(t + acc) -> slice0 (+ f32 out on last layer)
    ln_k<<<(M + 3) / 4, 256, 0, stream>>>(cat, CW, accb, ln2_g + mi * HD, ln2_b + mi * HD,
                                          cat, outf, M, 0);
  };

  for (int l = 0; l < L; l++) {
    segsum_k<<<(NN + 3) / 4, 256, 0, stream>>>(inc_offs, inc_cols, lg_cat, CW,
                                               n_cat + (size_t)(KH + 1) * HD, CW, NN);
    gather2_k<<<(NE + 3) / 4, 256, 0, stream>>>(eig, eig + NE, n_cat, CW,
                                                lg_cat + (size_t)(KH + 1) * HD, CW, NE);
    run_core(n_cat, acc_n, ng_offs, ng_cols, NN, l, 0, (l == L - 1) ? out_x : nullptr);
    run_core(lg_cat, acc_e, lg_offs, lg_cols, NE, l, 1, (l == L - 1) ? out_lg : nullptr);
  }
}

// Round 5
// 3038.400 us; speedup vs baseline: 1.3612x; 1.3612x over previous
//
#include <hip/hip_runtime.h>

typedef __bf16 bf16;
typedef __attribute__((ext_vector_type(8))) __bf16 bf16x8;
typedef __attribute__((ext_vector_type(4))) __bf16 bf16x4;
typedef __attribute__((ext_vector_type(4))) float f32x4;

#define HD 256
#define GEMM_GELU 2
#define GEMM_LN1  4   // out = LN(X + gelu(acc+bias))  (node/edge core LN1)
#define GEMM_LN2  8   // out = LN(X + acc+bias)        (FFN residual LN2)
#define GEMM_F32  16  // also write f32 rows to outf (stride HD)

// fast gelu: tanh form via hardware exp. |err vs exact erf-gelu| <= ~0.004,
// well inside the bf16 tolerance; ~8 VALU ops vs ~30 for erff.
__device__ __forceinline__ float gelu_f(float x) {
  float x2 = x * x;
  float u = 1.5957691216057308f * x * fmaf(0.044715f, x2, 1.0f);
  float e = __expf(-u);               // v_exp_f32
  return x / (1.0f + e);              // x * sigmoid(u)
}

__device__ __forceinline__ void gload_lds16(const void* g, void* l) {
  __builtin_amdgcn_global_load_lds(
      (const __attribute__((address_space(1))) unsigned int*)g,
      (__attribute__((address_space(3))) unsigned int*)l, 16, 0, 0);
}

// ---------------- GEMM: C[M,N] = epi(A[M,K] @ W[K,N] + bias) ----------------
// A: [M,*] bf16 row-stride lda.  Wt: [N,Kd] bf16 (pre-transposed, contiguous).
// C: [M,*] bf16 row-stride ldc.  N = gridDim.x*256.
// v6: BM=64 x BN=256 x BK=64, 4 waves (wave w owns cols w*64..w*64+63), R3's
// proven schedule (2-buf ring, counted vmcnt(10), raw barriers).
// WHY BN=256: rounds 0-3 showed combined HBM+LLC delivery pinned at ~4.5 TB/s;
// the 2nd N-block's duplicate A stream (491 MB LLC) was half of it. One N-block
// reads A exactly once. And with the full 256-ch row resident in the block,
// residual+gelu+LayerNorm fuse into the epilogue (kills ln_k kernels + the
// acc intermediate write/read: ~330 MB/iter).
__global__ __launch_bounds__(256) void gemm_k(
    const bf16* __restrict__ A, const bf16* __restrict__ Wt,
    const float* __restrict__ bias, bf16* __restrict__ C,
    const bf16* __restrict__ Xres, const float* __restrict__ gam,
    const float* __restrict__ bet, float* __restrict__ outf,
    int M, int Kd, int lda, int ldc, int flags)
{
  __shared__ __align__(16) bf16 sA[2][64 * 64];    //  8 KB x2
  __shared__ __align__(16) bf16 sB[2][256 * 64];   // 32 KB x2 -> 80 KB, 2 blk/CU
  const int t = threadIdx.x;
  const int lane = t & 63, w = t >> 6;
  const int n0 = blockIdx.x * 256, m0 = blockIdx.y * 64;
  const int lm = lane & 15, quad = lane >> 4;
  const int rowl = lane >> 3;                    // 0..7 within an 8-row group
  const int gcl = (lane & 7) ^ rowl;             // source chunk (16 B units)
  const bool full = (m0 + 64 <= M);

  // staging (XOR swizzle): chunk gc of row r lands at LDS slot gc^(r&7).
  // gload dest is linear (base + lane*16B); source addr carries the XOR.
  const char* pa = (const char*)(A + (size_t)(m0 + w * 16 + rowl) * lda) + gcl * 16;
  const char* pb = (const char*)(Wt + (size_t)(n0 + w * 64 + rowl) * Kd) + gcl * 16;
  const size_t stepA = (size_t)8 * lda * 2;      // 8 rows of A, bytes
  const size_t stepB = (size_t)8 * Kd * 2;       // 8 rows of Wt, bytes

  f32x4 acc[4][4];
#pragma unroll
  for (int i = 0; i < 4; i++)
#pragma unroll
    for (int j = 0; j < 4; j++)
#pragma unroll
      for (int r = 0; r < 4; r++) acc[i][j][r] = 0.f;

  const int nk = Kd >> 6;   // K-tiles of 64 (Kd in {256,1024,1536})

  auto stage = [&](bf16* SA, bf16* SB, int kt) {   // 10 gload_lds per wave
    size_t ko = (size_t)kt * 128;                  // 64 k-elems * 2 B
    gload_lds16(pa + ko, SA + w * 1024);
    gload_lds16(pa + stepA + ko, SA + w * 1024 + 512);
#pragma unroll
    for (int i = 0; i < 8; i++)
      gload_lds16(pb + i * stepB + ko, SB + w * 4096 + i * 512);
  };

  auto compute = [&](const bf16* SA, const bf16* SB) {
#pragma unroll
    for (int s = 0; s < 2; s++) {
      const int so = ((s * 4 + quad) ^ (lm & 7)) * 8;   // slot = chunk^(row&7)
      bf16x8 af[4], bv[4];
#pragma unroll
      for (int i = 0; i < 4; i++)
        af[i] = *(const bf16x8*)(SA + (i * 16 + lm) * 64 + so);
#pragma unroll
      for (int j = 0; j < 4; j++)
        bv[j] = *(const bf16x8*)(SB + (w * 64 + j * 16 + lm) * 64 + so);
      // swapped operands: D[n][m] -> acc[i][j] row = n (quad*4+r), col = m (lm)
#pragma unroll
      for (int i = 0; i < 4; i++)
#pragma unroll
        for (int j = 0; j < 4; j++)
          acc[i][j] = __builtin_amdgcn_mfma_f32_16x16x32_bf16(bv[j], af[i], acc[i][j], 0, 0, 0);
    }
  };

  if (full) {
    stage(sA[0], sB[0], 0);
    for (int kt = 0; kt < nk; ++kt) {
      if (kt + 1 < nk) {
        stage(sA[(kt + 1) & 1], sB[(kt + 1) & 1], kt + 1);
        asm volatile("s_waitcnt vmcnt(10)" ::: "memory");  // tile kt landed
      } else {
        asm volatile("s_waitcnt vmcnt(0)" ::: "memory");
      }
      __builtin_amdgcn_s_barrier();
      asm volatile("" ::: "memory");
      compute(sA[kt & 1], sB[kt & 1]);
      __builtin_amdgcn_s_barrier();      // protect buf before next stage
      asm volatile("" ::: "memory");
    }
  } else {
    // tail block-row (M%64, node grids only): drain-everything schedule.
    for (int kt = 0; kt < nk; ++kt) {
      size_t koe = (size_t)kt * 64;      // elements
#pragma unroll
      for (int i = 0; i < 2; i++) {
        int row = w * 16 + i * 8 + rowl;
        int gr = m0 + row;
        bf16x8 va;
#pragma unroll
        for (int q = 0; q < 8; q++) va[q] = (bf16)0.f;
        if (gr < M) va = *(const bf16x8*)(A + (size_t)gr * lda + koe + gcl * 8);
        *(bf16x8*)(sA[0] + row * 64 + (lane & 7) * 8) = va;
      }
#pragma unroll
      for (int i = 0; i < 8; i++)
        gload_lds16(pb + i * stepB + koe * 2, sB[0] + w * 4096 + i * 512);
      __syncthreads();
      compute(sA[0], sB[0]);
      __syncthreads();
    }
  }

  // ---- epilogue ----
  // thread (w,quad,lm) holds rows m0+i*16+lm, cols n0+w*64+j*16+quad*4+r
  f32x4 bia[4];
#pragma unroll
  for (int j = 0; j < 4; j++)
    bia[j] = *(const f32x4*)(bias + n0 + w * 64 + j * 16 + quad * 4);

  if (flags & (GEMM_LN1 | GEMM_LN2)) {
    // fused residual (+gelu) + LayerNorm over the 256-ch row (n0==0, N==256).
    float* ps = (float*)&sA[0][0];       // [64][16] partial sums (reuse LDS)
    float* pq = ps + 64 * 16;            // [64][16] partial sumsq
#pragma unroll
    for (int i = 0; i < 4; i++) {
      int gr = m0 + i * 16 + lm;
      float lsum = 0.f, lsq = 0.f;
#pragma unroll
      for (int j = 0; j < 4; j++) {
        bf16x4 xv = {(bf16)0.f, (bf16)0.f, (bf16)0.f, (bf16)0.f};
        if (gr < M) xv = *(const bf16x4*)(Xres + (size_t)gr * ldc + w * 64 + j * 16 + quad * 4);
#pragma unroll
        for (int r = 0; r < 4; r++) {
          float v = acc[i][j][r] + bia[j][r];
          if (flags & GEMM_LN1) v = gelu_f(v);
          v += (float)xv[r];
          acc[i][j][r] = v;
          lsum += v; lsq += v * v;
        }
      }
      ps[(i * 16 + lm) * 16 + w * 4 + quad] = lsum;
      pq[(i * 16 + lm) * 16 + w * 4 + quad] = lsq;
    }
    __syncthreads();
#pragma unroll
    for (int i = 0; i < 4; i++) {
      int gr = m0 + i * 16 + lm;
      float sum = 0.f, sq = 0.f;
#pragma unroll
      for (int k = 0; k < 16; k++) {
        sum += ps[(i * 16 + lm) * 16 + k];
        sq  += pq[(i * 16 + lm) * 16 + k];
      }
      float mean = sum * (1.0f / 256.0f);
      float var = sq * (1.0f / 256.0f) - mean * mean;
      float rstd = rsqrtf(fmaxf(var, 0.f) + 1e-5f);
      if (gr < M) {
        bf16* crow = C + (size_t)gr * ldc;
        float* frow = (flags & GEMM_F32) ? (outf + (size_t)gr * HD) : nullptr;
#pragma unroll
        for (int j = 0; j < 4; j++) {
          int gc = w * 64 + j * 16 + quad * 4;
          f32x4 g = *(const f32x4*)(gam + gc);
          f32x4 bb = *(const f32x4*)(bet + gc);
          float y0 = (acc[i][j][0] - mean) * rstd * g[0] + bb[0];
          float y1 = (acc[i][j][1] - mean) * rstd * g[1] + bb[1];
          float y2 = (acc[i][j][2] - mean) * rstd * g[2] + bb[2];
          float y3 = (acc[i][j][3] - mean) * rstd * g[3] + bb[3];
          bf16x4 o = {(bf16)y0, (bf16)y1, (bf16)y2, (bf16)y3};
          *(bf16x4*)(crow + gc) = o;
          if (frow) { f32x4 fo = {y0, y1, y2, y3}; *(f32x4*)(frow + gc) = fo; }
        }
      }
    }
  } else {
#pragma unroll
    for (int i = 0; i < 4; i++) {
      int gr = m0 + i * 16 + lm;
      if (gr < M) {
        bf16* crow = C + (size_t)gr * ldc;
#pragma unroll
        for (int j = 0; j < 4; j++) {
          int gc = n0 + w * 64 + j * 16 + quad * 4;
          float v0 = acc[i][j][0] + bia[j][0];
          float v1 = acc[i][j][1] + bia[j][1];
          float v2 = acc[i][j][2] + bia[j][2];
          float v3 = acc[i][j][3] + bia[j][3];
          if (flags & GEMM_GELU) {
            v0 = gelu_f(v0); v1 = gelu_f(v1); v2 = gelu_f(v2); v3 = gelu_f(v3);
          }
          bf16x4 o = {(bf16)v0, (bf16)v1, (bf16)v2, (bf16)v3};
          *(bf16x4*)(crow + gc) = o;
        }
      }
    }
  }
}

// ---------------- segment sum via CSR (strided rows) ----------------
// v6: unrolled x4 so 4 gather rows are in flight per wave (adds stay in
// ascending-i order -> bit-identical to the serial loop).
__global__ __launch_bounds__(256) void segsum_k(
    const int* __restrict__ offs, const int* __restrict__ cols,
    const bf16* __restrict__ in, int ldin, bf16* __restrict__ out, int ldout, int nseg)
{
  int wid = threadIdx.x >> 6, lane = threadIdx.x & 63;
  int seg = blockIdx.x * 4 + wid;
  if (seg >= nseg) return;
  int b = offs[seg], e = offs[seg + 1];
  float a0 = 0.f, a1 = 0.f, a2 = 0.f, a3 = 0.f;
  int i = b;
  for (; i + 4 <= e; i += 4) {
    int c0 = cols[i], c1 = cols[i + 1], c2 = cols[i + 2], c3 = cols[i + 3];
    bf16x4 v0 = *(const bf16x4*)(in + (size_t)c0 * ldin + lane * 4);
    bf16x4 v1 = *(const bf16x4*)(in + (size_t)c1 * ldin + lane * 4);
    bf16x4 v2 = *(const bf16x4*)(in + (size_t)c2 * ldin + lane * 4);
    bf16x4 v3 = *(const bf16x4*)(in + (size_t)c3 * ldin + lane * 4);
    a0 += (float)v0.x; a1 += (float)v0.y; a2 += (float)v0.z; a3 += (float)v0.w;
    a0 += (float)v1.x; a1 += (float)v1.y; a2 += (float)v1.z; a3 += (float)v1.w;
    a0 += (float)v2.x; a1 += (float)v2.y; a2 += (float)v2.z; a3 += (float)v2.w;
    a0 += (float)v3.x; a1 += (float)v3.y; a2 += (float)v3.z; a3 += (float)v3.w;
  }
  for (; i < e; i++) {
    int c = cols[i];
    bf16x4 v = *(const bf16x4*)(in + (size_t)c * ldin + lane * 4);
    a0 += (float)v.x; a1 += (float)v.y; a2 += (float)v.z; a3 += (float)v.w;
  }
  bf16x4 o = {(bf16)a0, (bf16)a1, (bf16)a2, (bf16)a3};
  *(bf16x4*)(out + (size_t)seg * ldout + lane * 4) = o;
}

// ---------------- lg_x init ----------------
__global__ __launch_bounds__(256) void gather_rel_k(
    const int* __restrict__ feat, const float* __restrict__ rel,
    bf16* __restrict__ out, int ldout, int NE)
{
  int wid = threadIdx.x >> 6, lane = threadIdx.x & 63;
  int e = blockIdx.x * 4 + wid;
  if (e >= NE) return;
  int f = feat[e];
  float4 v = *(const float4*)(rel + (size_t)f * HD + lane * 4);
  bf16x4 o = {(bf16)v.x, (bf16)v.y, (bf16)v.z, (bf16)v.w};
  *(bf16x4*)(out + (size_t)e * ldout + lane * 4) = o;
}

// ---------------- fused_edges: out[e] = x[src[e]] + x[dst[e]] ----------------
__global__ __launch_bounds__(256) void gather2_k(
    const int* __restrict__ src, const int* __restrict__ dst,
    const bf16* __restrict__ x, int ldx, bf16* __restrict__ out, int ldout, int NE)
{
  int wid = threadIdx.x >> 6, lane = threadIdx.x & 63;
  int e = blockIdx.x * 4 + wid;
  if (e >= NE) return;
  int s = src[e], d = dst[e];
  bf16x4 a = *(const bf16x4*)(x + (size_t)s * ldx + lane * 4);
  bf16x4 b = *(const bf16x4*)(x + (size_t)d * ldx + lane * 4);
  bf16x4 o = {(bf16)((float)a.x + (float)b.x), (bf16)((float)a.y + (float)b.y),
              (bf16)((float)a.z + (float)b.z), (bf16)((float)a.w + (float)b.w)};
  *(bf16x4*)(out + (size_t)e * ldout + lane * 4) = o;
}

// ---------------- f32 row copy -> bf16 strided ----------------
__global__ __launch_bounds__(256) void f2b_k(const float* __restrict__ in,
                                             bf16* __restrict__ out, int ldout, int M) {
  int wid = threadIdx.x >> 6, lane = threadIdx.x & 63;
  int row = blockIdx.x * 4 + wid;
  if (row >= M) return;
  float4 v = *(const float4*)(in + (size_t)row * HD + lane * 4);
  bf16x4 o = {(bf16)v.x, (bf16)v.y, (bf16)v.z, (bf16)v.w};
  *(bf16x4*)(out + (size_t)row * ldout + lane * 4) = o;
}

// ---------------- weight transpose+convert ----------------
__global__ __launch_bounds__(256) void wtrans_k(const float* __restrict__ in, bf16* __restrict__ out,
                                                int Kd, int Nd) {
  size_t moff = (size_t)blockIdx.y * Kd * Nd;
  int id = blockIdx.x * 256 + threadIdx.x;
  if (id >= Kd * Nd) return;
  int n = id / Kd, k = id - n * Kd;
  out[moff + id] = (bf16)in[moff + (size_t)k * Nd + n];
}

// ---------------- cat weight build ----------------
__global__ __launch_bounds__(256) void wcat_k(const float* __restrict__ ws, const float* __restrict__ wk,
                                              const float* __restrict__ wf, bf16* __restrict__ out,
                                              int KH, int CW) {
  int mi = blockIdx.y;
  int id = blockIdx.x * 256 + threadIdx.x;
  if (id >= HD * CW) return;
  int n = id / CW, k = id - n * CW;
  int s = k >> 8, kk = k & 255;
  float v;
  if (s == 0)       v = ws[((size_t)mi * HD + kk) * HD + n];
  else if (s <= KH) v = wk[(((size_t)mi * KH + (s - 1)) * HD + kk) * HD + n];
  else              v = wf[((size_t)mi * HD + kk) * HD + n];
  out[(size_t)mi * HD * CW + id] = (bf16)v;
}

// ---------------- cat bias ----------------
__global__ __launch_bounds__(256) void bcat_k(const float* __restrict__ bs, const float* __restrict__ bk,
                                              const float* __restrict__ bf, float* __restrict__ out, int KH) {
  int mi = blockIdx.x, n = threadIdx.x;
  float v = bs[(size_t)mi * HD + n] + bf[(size_t)mi * HD + n];
  for (int i = 0; i < KH; i++) v += bk[((size_t)mi * KH + i) * HD + n];
  out[(size_t)mi * HD + n] = v;
}

// ---------------- CSR build ----------------
__global__ __launch_bounds__(256) void count_k(const int* __restrict__ keys, int n, int* __restrict__ cnt) {
  int i = blockIdx.x * 256 + threadIdx.x;
  if (i < n) atomicAdd(&cnt[keys[i]], 1);
}
__global__ __launch_bounds__(256) void scan1_k(const int* __restrict__ in, int* __restrict__ out,
                                               int* __restrict__ bsum, int n) {
  __shared__ int sh[256];
  int t = threadIdx.x;
  int i0 = blockIdx.x * 1024 + t * 4;
  int v0 = (i0 < n) ? in[i0] : 0;
  int v1 = (i0 + 1 < n) ? in[i0 + 1] : 0;
  int v2 = (i0 + 2 < n) ? in[i0 + 2] : 0;
  int v3 = (i0 + 3 < n) ? in[i0 + 3] : 0;
  int tsum = v0 + v1 + v2 + v3;
  sh[t] = tsum;
  __syncthreads();
  for (int o = 1; o < 256; o <<= 1) {
    int x = (t >= o) ? sh[t - o] : 0;
    __syncthreads();
    sh[t] += x;
    __syncthreads();
  }
  int e0 = sh[t] - tsum;
  if (t == 255) bsum[blockIdx.x] = sh[255];
  if (i0 < n) out[i0] = e0;
  e0 += v0;
  if (i0 + 1 < n) out[i0 + 1] = e0;
  e0 += v1;
  if (i0 + 2 < n) out[i0 + 2] = e0;
  e0 += v2;
  if (i0 + 3 < n) out[i0 + 3] = e0;
}
__global__ void scan2_k(int* bsum, int nb, int* total) {
  if (threadIdx.x == 0 && blockIdx.x == 0) {
    int acc = 0;
    for (int i = 0; i < nb; i++) { int v = bsum[i]; bsum[i] = acc; acc += v; }
    *total = acc;
  }
}
__global__ __launch_bounds__(256) void scan3_k(int* out, const int* bsum, int n) {
  int i = blockIdx.x * 256 + threadIdx.x;
  if (i < n) out[i] += bsum[i >> 10];
}
__global__ __launch_bounds__(256) void fill_k(const int* __restrict__ keys, const int* __restrict__ vals,
                                              int n, int modE, int* __restrict__ cursor, int* __restrict__ cols) {
  int i = blockIdx.x * 256 + threadIdx.x;
  if (i >= n) return;
  int pos = atomicAdd(&cursor[keys[i]], 1);
  cols[pos] = vals ? vals[i] : (i < modE ? i : i - modE);
}

extern "C" void kernel_launch(void* const* d_in, const int* in_sizes, int n_in,
                              void* d_out, int out_size, void* d_ws, size_t ws_size,
                              hipStream_t stream)
{
  const float* x_in      = (const float*)d_in[0];
  const int*   edge_feat = (const int*)d_in[1];
  const int*   eig       = (const int*)d_in[2];
  const int*   eil       = (const int*)d_in[3];
  const float* rel       = (const float*)d_in[4];
  const float* w_self = (const float*)d_in[5];
  const float* b_self = (const float*)d_in[6];
  const float* w_khop = (const float*)d_in[7];
  const float* b_khop = (const float*)d_in[8];
  const float* w_fuse = (const float*)d_in[9];
  const float* b_fuse = (const float*)d_in[10];
  const float* w_ff1  = (const float*)d_in[11];
  const float* b_ff1  = (const float*)d_in[12];
  const float* w_ff2  = (const float*)d_in[13];
  const float* b_ff2  = (const float*)d_in[14];
  const float* ln1_g  = (const float*)d_in[15];
  const float* ln1_b  = (const float*)d_in[16];
  const float* ln2_g  = (const float*)d_in[17];
  const float* ln2_b  = (const float*)d_in[18];

  const int NN = in_sizes[0] / HD;
  const int NE = in_sizes[1];
  const int NL = in_sizes[3] / 2;
  const int L  = in_sizes[5] / (2 * HD * HD);
  const int KH = in_sizes[7] / (L * 2 * HD * HD);
  const int CW = (KH + 2) * HD;   // cat width: x | z1..zKH | fused

  char* p = (char*)d_ws;
  auto alloc = [&](size_t bytes) -> void* {
    void* r = (void*)p;
    p += (bytes + 255) & ~(size_t)255;
    return r;
  };

  bf16* n_cat  = (bf16*)alloc((size_t)NN * CW * 2);
  bf16* lg_cat = (bf16*)alloc((size_t)NE * CW * 2);

  bf16*  wcat_t = (bf16*)alloc((size_t)L * 2 * HD * CW * 2);
  float* bcat   = (float*)alloc((size_t)L * 2 * HD * 4);
  bf16*  wff1_t = (bf16*)alloc((size_t)L * 2 * HD * 4 * HD * 2);
  bf16*  wff2_t = (bf16*)alloc((size_t)L * 2 * HD * 4 * HD * 2);

  int* inc_offs = (int*)alloc((size_t)(NN + 1) * 4);
  int* inc_cur  = (int*)alloc((size_t)NN * 4);
  int* inc_cols = (int*)alloc((size_t)2 * NE * 4);
  int* ng_offs  = (int*)alloc((size_t)(NN + 1) * 4);
  int* ng_cur   = (int*)alloc((size_t)NN * 4);
  int* ng_cols  = (int*)alloc((size_t)NE * 4);
  int* lg_offs  = (int*)alloc((size_t)(NE + 1) * 4);
  int* lg_cur   = (int*)alloc((size_t)NE * 4);
  int* lg_cols  = (int*)alloc((size_t)NL * 4);
  int* bsum     = (int*)alloc(3 * 256 * 4);

  // ---- weights ----
  wcat_k<<<dim3((HD * CW + 255) / 256, L * 2), 256, 0, stream>>>(w_self, w_khop, w_fuse, wcat_t, KH, CW);
  bcat_k<<<L * 2, 256, 0, stream>>>(b_self, b_khop, b_fuse, bcat, KH);
  wtrans_k<<<dim3((HD * 4 * HD + 255) / 256, L * 2), 256, 0, stream>>>(w_ff1, wff1_t, HD, 4 * HD);
  wtrans_k<<<dim3((HD * 4 * HD + 255) / 256, L * 2), 256, 0, stream>>>(w_ff2, wff2_t, 4 * HD, HD);

  // ---- activation init ----
  f2b_k<<<(NN + 3) / 4, 256, 0, stream>>>(x_in, n_cat, CW, NN);
  gather_rel_k<<<(NE + 3) / 4, 256, 0, stream>>>(edge_feat, rel, lg_cat, CW, NE);

  // ---- CSR builds ----
  auto build_csr = [&](const int* keys, int nkeys, const int* vals, int modE,
                       int nseg, int* offs, int* cur, int* cols, int* bs) {
    int nb = (nseg + 1023) / 1024;
    hipMemsetAsync(offs, 0, (size_t)(nseg + 1) * 4, stream);
    count_k<<<(nkeys + 255) / 256, 256, 0, stream>>>(keys, nkeys, offs);
    scan1_k<<<nb, 256, 0, stream>>>(offs, offs, bs, nseg);
    scan2_k<<<1, 1, 0, stream>>>(bs, nb, offs + nseg);
    scan3_k<<<(nseg + 255) / 256, 256, 0, stream>>>(offs, bs, nseg);
    hipMemcpyAsync(cur, offs, (size_t)nseg * 4, hipMemcpyDeviceToDevice, stream);
    fill_k<<<(nkeys + 255) / 256, 256, 0, stream>>>(keys, vals, nkeys, modE, cur, cols);
  };
  build_csr(eig, 2 * NE, nullptr, NE, NN, inc_offs, inc_cur, inc_cols, bsum);
  build_csr(eig + NE, NE, eig, 0, NN, ng_offs, ng_cur, ng_cols, bsum + 256);
  build_csr(eil + NL, NL, eil, 0, NE, lg_offs, lg_cur, lg_cols, bsum + 512);

  float* out_x  = (float*)d_out;
  float* out_lg = (float*)d_out + (size_t)NN * HD;

  auto run_core = [&](bf16* cat, const int* coffs, const int* ccols,
                      int M, int l, int c, float* outf) {
    size_t mi = (size_t)(l * 2 + c);
    // khop chain into slices 1..KH
    for (int i = 1; i <= KH; i++)
      segsum_k<<<(M + 3) / 4, 256, 0, stream>>>(coffs, ccols, cat + (size_t)(i - 1) * HD, CW,
                                                cat + (size_t)i * HD, CW, M);
    // slice0 = LN1(x + gelu(cat @ Wcat + bcat))  -- fused epilogue
    gemm_k<<<dim3(1, (M + 63) / 64), 256, 0, stream>>>(
        cat, wcat_t + mi * HD * CW, bcat + mi * HD, cat,
        cat, ln1_g + mi * HD, ln1_b + mi * HD, nullptr,
        M, CW, CW, CW, GEMM_LN1);
    // FFN chunked through scratch (slices 1..4, rows [0,FC)) for LLC residency
    bf16* hid = cat + HD;
    int FC = (M > 40000) ? 40000 : M;
    for (int c0 = 0; c0 < M; c0 += FC) {
      int mc = (M - c0 < FC) ? (M - c0) : FC;
      gemm_k<<<dim3(4, (mc + 63) / 64), 256, 0, stream>>>(
          cat + (size_t)c0 * CW, wff1_t + mi * HD * 4 * HD, b_ff1 + mi * 4 * HD, hid,
          nullptr, nullptr, nullptr, nullptr, mc, HD, CW, CW, GEMM_GELU);
      // slice0 = LN2(t + hid @ Wff2 + b2)  -- fused epilogue (+f32 out last layer)
      gemm_k<<<dim3(1, (mc + 63) / 64), 256, 0, stream>>>(
          hid, wff2_t + mi * 4 * HD * HD, b_ff2 + mi * HD, cat + (size_t)c0 * CW,
          cat + (size_t)c0 * CW, ln2_g + mi * HD, ln2_b + mi * HD,
          outf ? outf + (size_t)c0 * HD : nullptr,
          mc, 4 * HD, CW, CW, GEMM_LN2 | (outf ? GEMM_F32 : 0));
    }
  };

  for (int l = 0; l < L; l++) {
    segsum_k<<<(NN + 3) / 4, 256, 0, stream>>>(inc_offs, inc_cols, lg_cat, CW,
                                               n_cat + (size_t)(KH + 1) * HD, CW, NN);
    gather2_k<<<(NE + 3) / 4, 256, 0, stream>>>(eig, eig + NE, n_cat, CW,
                                                lg_cat + (size_t)(KH + 1) * HD, CW, NE);
    run_core(n_cat, ng_offs, ng_cols, NN, l, 0, (l == L - 1) ? out_x : nullptr);
    run_core(lg_cat, lg_offs, lg_cols, NE, l, 1, (l == L - 1) ? out_lg : nullptr);
  }
}